// Round 6
// baseline (1039.004 us; speedup 1.0000x reference)
//
#include <hip/hip_runtime.h>
#include <hip/hip_bf16.h>
#include <math.h>

// ---------- types ----------
typedef __attribute__((ext_vector_type(8))) short bf16x8;  // 8 bf16 (4 VGPRs)
typedef __attribute__((ext_vector_type(4))) float f32x4;   // MFMA C/D frag

__device__ inline float bf2f(short u) {
  union { float f; unsigned int i; } v;
  v.i = ((unsigned int)(unsigned short)u) << 16;
  return v.f;
}
__device__ inline short f2bf(float f) {
  union { float f; unsigned int i; } v; v.f = f;
  unsigned int r = v.i + 0x7fff + ((v.i >> 16) & 1);  // RNE
  return (short)(r >> 16);
}

// ---------- prep: pad/transpose weights (tiny) ----------
__global__ void pad_T(const float* __restrict__ src, short* __restrict__ dst,
                      int K, int N, int Kp, int total) {
  int i = blockIdx.x * 256 + threadIdx.x;
  if (i >= total) return;
  int n = i / Kp, k = i - n * Kp;
  dst[i] = f2bf((k < K && n < N) ? src[(size_t)k * N + n] : 0.f);
}

// ---------- batched transpose: in [64][1024][320] -> out [64][320][1024] ----------
__global__ __launch_bounds__(256) void transpose_pd(const short* __restrict__ in,
                                                    short* __restrict__ out) {
  __shared__ unsigned int T[64][32];  // row p: 32 dwords (64 shorts)
  const int b = blockIdx.z, p0 = blockIdx.x * 64, d0 = blockIdx.y * 64;
  const short* ib = in + (size_t)b * 1024 * 320;
  short* ob = out + (size_t)b * 320 * 1024;
  for (int i = threadIdx.x; i < 512; i += 256) {
    int p = i >> 3, g = i & 7;
    uint4 v = *(const uint4*)&ib[(size_t)(p0 + p) * 320 + d0 + g * 8];
    int s = p & 31;
    T[p][(4 * g + 0) ^ s] = v.x;
    T[p][(4 * g + 1) ^ s] = v.y;
    T[p][(4 * g + 2) ^ s] = v.z;
    T[p][(4 * g + 3) ^ s] = v.w;
  }
  __syncthreads();
  for (int i = threadIdx.x; i < 512; i += 256) {
    int d = i >> 3, g = i & 7;
    int w0 = d >> 1;
    __align__(16) unsigned short tmp[8];
#pragma unroll
    for (int j = 0; j < 8; ++j) {
      int p = g * 8 + j;
      unsigned int val = T[p][w0 ^ (p & 31)];
      tmp[j] = (d & 1) ? (unsigned short)(val >> 16) : (unsigned short)(val & 0xffff);
    }
    *(uint4*)&ob[(size_t)(d0 + d) * 1024 + p0 + g * 8] = *(const uint4*)tmp;
  }
}

// ---------- unified MFMA GEMM (K>=320 cases: W1, W2) ----------
template<int NT, int MODE>
__global__ __launch_bounds__(512) void gemm_ep(
    const short* __restrict__ A, const short* __restrict__ Bt, int K,
    const float* __restrict__ bias, int biasN,
    void* __restrict__ outp, int outStride)
{
  __shared__ __align__(16) short Bst[NT][40];  // [n][k-tile 32], row 80B
  const int tid = threadIdx.x;
  const int wave = tid >> 6, lane = tid & 63;
  const int m = lane & 15, quad = lane >> 4;
  const int row0 = blockIdx.x * 128 + wave * 16;
  const int n0 = blockIdx.y * NT;

  f32x4 zero = {0.f, 0.f, 0.f, 0.f};
  f32x4 acc[NT / 16];
#pragma unroll
  for (int i = 0; i < NT / 16; ++i) acc[i] = zero;

  const short* arow = A + (size_t)(row0 + m) * K;

  for (int k0 = 0; k0 < K; k0 += 32) {
    __syncthreads();
    for (int idx = tid; idx < NT * 4; idx += 512) {
      int n = idx >> 2, kc = (idx & 3) << 3;
      *(uint4*)&Bst[n][kc] = *(const uint4*)&Bt[(size_t)(n0 + n) * K + k0 + kc];
    }
    __syncthreads();
    bf16x8 af = *(const bf16x8*)(arow + k0 + quad * 8);
#pragma unroll
    for (int nt = 0; nt < NT / 16; ++nt) {
      bf16x8 bf = *(const bf16x8*)&Bst[nt * 16 + m][quad * 8];
      acc[nt] = __builtin_amdgcn_mfma_f32_16x16x32_bf16(af, bf, acc[nt], 0, 0, 0);
    }
  }

#pragma unroll
  for (int nt = 0; nt < NT / 16; ++nt) {
#pragma unroll
    for (int r = 0; r < 4; ++r) {
      int row = row0 + quad * 4 + r;
      int col = n0 + nt * 16 + m;
      float v = acc[nt][r];
      if (MODE != 0) v += (col < biasN) ? bias[col] : 0.f;
      if (MODE == 1) v = tanhf(v);
      if (MODE == 2) v = fmaxf(v, 0.f);
      if (MODE == 3)
        ((float*)outp)[(size_t)row * outStride + col] = v;
      else
        ((short*)outp)[(size_t)row * outStride + col] = f2bf(v);
    }
  }
}

// ---------- small-K fused GEMM: A fp32 [rows][50] direct, B direct from L2 ----------
// K=64 (padded), N=320. Block 512 thr = 8 waves x 16 rows = 128 rows. No LDS, no
// barriers: B (40 KB/output) is identical across all blocks -> L1/L2-hot direct reads.
// NOUT outputs share one A read. Modes: 1 = tanh(v+bias); 4 = LayerNorm (gamma,beta)
// fused in-register (per-row sums live in 16 m-lanes x 20 accs; shfl_xor reduce).
template<int NOUT, int M0, int M1>
__global__ __launch_bounds__(512) void gemm_small(
    const float* __restrict__ A,
    const short* __restrict__ B0, const float* __restrict__ p00, const float* __restrict__ p01,
    const short* __restrict__ B1, const float* __restrict__ p10, const float* __restrict__ p11,
    short* __restrict__ out0, short* __restrict__ out1)
{
  const int tid = threadIdx.x;
  const int wave = tid >> 6, lane = tid & 63;
  const int m = lane & 15, quad = lane >> 4;
  const int row = blockIdx.x * 128 + wave * 16 + m;

  // A fragments: fp32 -> bf16, pad k 50->64 with zeros (replaces pad_rows)
  bf16x8 af[2];
#pragma unroll
  for (int c = 0; c < 2; ++c) {
    union { short s[8]; bf16x8 v; } u;
#pragma unroll
    for (int j = 0; j < 8; ++j) {
      int k = c * 32 + quad * 8 + j;
      u.s[j] = f2bf(k < 50 ? A[(size_t)row * 50 + k] : 0.f);
    }
    af[c] = u.v;
  }

#pragma unroll
  for (int o = 0; o < NOUT; ++o) {
    const short* Bt = o ? B1 : B0;
    const float* pa = o ? p10 : p00;
    const float* pb = o ? p11 : p01;
    short* outp = o ? out1 : out0;
    const int mode = o ? M1 : M0;

    f32x4 acc[20];
#pragma unroll
    for (int i = 0; i < 20; ++i) acc[i] = {0.f, 0.f, 0.f, 0.f};
#pragma unroll
    for (int c = 0; c < 2; ++c) {
      bf16x8 bf[20];  // batched: 20 loads in flight, then 20 MFMAs
#pragma unroll
      for (int nt = 0; nt < 20; ++nt)
        bf[nt] = *(const bf16x8*)&Bt[(size_t)(nt * 16 + m) * 64 + c * 32 + quad * 8];
#pragma unroll
      for (int nt = 0; nt < 20; ++nt)
        acc[nt] = __builtin_amdgcn_mfma_f32_16x16x32_bf16(af[c], bf[nt], acc[nt], 0, 0, 0);
    }

    const int rbase = blockIdx.x * 128 + wave * 16 + quad * 4;
    if (mode == 1) {  // tanh(v + bias)
#pragma unroll
      for (int r = 0; r < 4; ++r) {
        const size_t rw = (size_t)(rbase + r) * 320;
#pragma unroll
        for (int nt = 0; nt < 20; ++nt) {
          int col = nt * 16 + m;
          float v = acc[nt][r] + ((col < 300) ? pa[col] : 0.f);
          outp[rw + col] = f2bf(tanhf(v));  // cols>=300: acc=0,bias=0 -> 0
        }
      }
    } else {  // mode 4: LayerNorm over first 300 cols (weights zero-padded -> sums exact)
#pragma unroll
      for (int r = 0; r < 4; ++r) {
        float s = 0.f, ss = 0.f;
#pragma unroll
        for (int nt = 0; nt < 20; ++nt) { float v = acc[nt][r]; s += v; ss += v * v; }
#pragma unroll
        for (int off = 8; off > 0; off >>= 1) {
          s += __shfl_xor(s, off); ss += __shfl_xor(ss, off);
        }
        const float mu = s * (1.f / 300.f);
        const float rstd = rsqrtf(ss * (1.f / 300.f) - mu * mu + 1e-6f);
        const size_t rw = (size_t)(rbase + r) * 320;
#pragma unroll
        for (int nt = 0; nt < 20; ++nt) {
          int col = nt * 16 + m;
          float v = (col < 300) ? (pa[col] * (acc[nt][r] - mu) * rstd + pb[col]) : 0.f;
          outp[rw + col] = f2bf(v);
        }
      }
    }
  }
}

// ---------- helpers for attn ----------
__device__ inline void gload16(const short* g, short* l) {
  __builtin_amdgcn_global_load_lds((const __attribute__((address_space(1))) void*)g,
                                   (__attribute__((address_space(3))) void*)l, 16, 0, 0);
}
__device__ inline void block_sync() {
  asm volatile("s_waitcnt vmcnt(0) lgkmcnt(0)" ::: "memory");
  __builtin_amdgcn_s_barrier();
  __builtin_amdgcn_sched_barrier(0);
}

// ---------- fused sigmoid-attention v6 (unchanged from R5, verified) ----------
__global__ __launch_bounds__(512, 2) void attn_v6(
    const short* __restrict__ Qm, const short* __restrict__ Km,
    const short* __restrict__ VT, const short* __restrict__ tokp,
    short* __restrict__ Outp)
{
  __shared__ __align__(16) short KsL[2][10240];  // [32 p][320 d], chunk^(p&7)
  __shared__ __align__(16) short VsL[2][10240];  // [320 d][32 p], chunk^(d&3)

  const int tid = threadIdx.x;
  const int wave = tid >> 6, lane = tid & 63;
  const int m = lane & 15, quad = lane >> 4;
  const int b = blockIdx.x;
  const int qrow0 = b * 1024 + blockIdx.y * 128;
  const size_t kbase = (size_t)b * 1024 * 320;
  const short* vtb = VT + (size_t)b * 320 * 1024;

  const short* src[5];
  int dst[5];
#pragma unroll
  for (int j = 0; j < 5; ++j) {
    int c = j * 512 + tid;
    if (c < 1280) {
      int p = c / 40, ch = c - p * 40;
      src[j] = Km + kbase + (size_t)p * 320 + ((ch ^ (p & 7)) << 3);
      dst[j] = c << 3;
    } else {
      int cv = c - 1280;
      int d = cv >> 2, ch = cv & 3;
      src[j] = vtb + (size_t)d * 1024 + ((ch ^ (d & 3)) << 3);
      dst[j] = cv << 3;
    }
  }
  const bool j2K = (wave < 4);

  auto stage = [&](int pt) {
    const int bb = pt & 1;
    gload16(src[0] + (size_t)pt * 10240, &KsL[bb][dst[0]]);
    gload16(src[1] + (size_t)pt * 10240, &KsL[bb][dst[1]]);
    if (j2K) gload16(src[2] + (size_t)pt * 10240, &KsL[bb][dst[2]]);
    else     gload16(src[2] + (size_t)pt * 32,    &VsL[bb][dst[2]]);
    gload16(src[3] + (size_t)pt * 32, &VsL[bb][dst[3]]);
    gload16(src[4] + (size_t)pt * 32, &VsL[bb][dst[4]]);
  };

  bf16x8 qf[10];
  const short* qb = Qm + (size_t)(qrow0 + wave * 16 + m) * 320;
#pragma unroll
  for (int c = 0; c < 10; ++c)
    qf[c] = *(const bf16x8*)(qb + c * 32 + quad * 8);

  f32x4 zero = {0.f, 0.f, 0.f, 0.f};
  f32x4 o[20];
#pragma unroll
  for (int i = 0; i < 20; ++i) o[i] = zero;

  const int vch = (quad ^ (m & 3)) << 3;
  const unsigned oddq = (unsigned)(quad & 1);

  stage(0);
  block_sync();

  for (int pt = 0; pt < 32; ++pt) {
    if (pt < 31) stage(pt + 1);
    const short* Kc = &KsL[pt & 1][0];
    const short* Vc = &VsL[pt & 1][0];

    f32x4 sl = zero, sh = zero;
#pragma unroll
    for (int c = 0; c < 10; ++c) {
      int ch0 = ((4 * c + quad) ^ (m & 7)) << 3;
      bf16x8 k0 = *(const bf16x8*)&Kc[m * 320 + ch0];
      bf16x8 k1 = *(const bf16x8*)&Kc[(m + 16) * 320 + ch0];
      sl = __builtin_amdgcn_mfma_f32_16x16x32_bf16(k0, qf[c], sl, 0, 0, 0);
      sh = __builtin_amdgcn_mfma_f32_16x16x32_bf16(k1, qf[c], sh, 0, 0, 0);
    }

    float e0[4], e1[4];
#pragma unroll
    for (int r = 0; r < 4; ++r) {
      e0[r] = 1.f / (1.f + __expf(-sl[r]));
      e1[r] = 1.f / (1.f + __expf(-sh[r]));
    }
    int w0, w1, w2, w3;
    asm("v_cvt_pk_bf16_f32 %0, %1, %2" : "=v"(w0) : "v"(e0[0]), "v"(e0[1]));
    asm("v_cvt_pk_bf16_f32 %0, %1, %2" : "=v"(w1) : "v"(e0[2]), "v"(e0[3]));
    asm("v_cvt_pk_bf16_f32 %0, %1, %2" : "=v"(w2) : "v"(e1[0]), "v"(e1[1]));
    asm("v_cvt_pk_bf16_f32 %0, %1, %2" : "=v"(w3) : "v"(e1[2]), "v"(e1[3]));

    int x0 = w0, y0 = w2, x1 = w1, y1 = w3;
    asm volatile("v_permlane32_swap_b32 %0, %1" : "+v"(x0), "+v"(y0));
    asm volatile("v_permlane32_swap_b32 %0, %1" : "+v"(x1), "+v"(y1));
    int sx0 = __builtin_amdgcn_ds_swizzle(x0, 0x401f);
    int sy0 = __builtin_amdgcn_ds_swizzle(y0, 0x401f);
    int sx1 = __builtin_amdgcn_ds_swizzle(x1, 0x401f);
    int sy1 = __builtin_amdgcn_ds_swizzle(y1, 0x401f);
    union { int i[4]; bf16x8 v; } pu;
    pu.i[0] = oddq ? sy0 : x0;
    pu.i[1] = oddq ? sy1 : x1;
    pu.i[2] = oddq ? y0 : sx0;
    pu.i[3] = oddq ? y1 : sx1;
    bf16x8 pa = pu.v;

#pragma unroll
    for (int dt = 0; dt < 20; ++dt) {
      bf16x8 vb = *(const bf16x8*)&Vc[(dt * 16 + m) * 32 + vch];
      o[dt] = __builtin_amdgcn_mfma_f32_16x16x32_bf16(pa, vb, o[dt], 0, 0, 0);
    }

    block_sync();
  }

#pragma unroll
  for (int dt = 0; dt < 20; ++dt)
#pragma unroll
    for (int r = 0; r < 4; ++r) {
      const size_t row = (size_t)qrow0 + wave * 16 + quad * 4 + r;
      const int col = dt * 16 + m;
      float val = o[dt][r];
      if (tokp) val += bf2f(tokp[row * 320 + col]);
      Outp[row * 320 + col] = f2bf(val);
    }
}

// ---------- launch ----------
extern "C" void kernel_launch(void* const* d_in, const int* in_sizes, int n_in,
                              void* d_out, int out_size, void* d_ws, size_t ws_size,
                              hipStream_t stream)
{
  const float* x    = (const float*)d_in[0];
  const float* me   = (const float*)d_in[1];
  const float* past = (const float*)d_in[2];
  const float* wpt  = (const float*)d_in[3];
  const float* bpt  = (const float*)d_in[4];
  const float* wpg  = (const float*)d_in[5];
  const float* bpg  = (const float*)d_in[6];
  const float* wps  = (const float*)d_in[7];
  const float* bps  = (const float*)d_in[8];
  const float* wex  = (const float*)d_in[9];
  const float* bex  = (const float*)d_in[10];
  const float* lng  = (const float*)d_in[11];
  const float* lnb  = (const float*)d_in[12];
  const float* W1   = (const float*)d_in[13];
  const float* b1   = (const float*)d_in[14];
  const float* W2   = (const float*)d_in[15];
  const float* b2   = (const float*)d_in[16];
  float* out = (float*)d_out;

  // ---- workspace (~201 MB) ----
  char* ws = (char*)d_ws;
  size_t off = 0;
  auto alloc = [&](size_t bytes) -> char* {
    char* p = ws + off; off += (bytes + 255) & ~(size_t)255; return p;
  };
  const size_t RB = 65536ull;
  short* wmeT  = (short*)alloc(320 * 64 * 2);
  short* wptT  = (short*)alloc(320 * 64 * 2);
  short* wpgT  = (short*)alloc(320 * 64 * 2);
  short* wpsT  = (short*)alloc(320 * 64 * 2);
  short* wexT  = (short*)alloc(320 * 64 * 2);
  short* w1T   = (short*)alloc(320 * 320 * 2);
  short* w2T   = (short*)alloc(1024ull * 320 * 2);
  short* buf0  = (short*)alloc(RB * 320 * 2);   // 40 MB: ptok -> filt
  short* buf1  = (short*)alloc(RB * 320 * 2);   // 40 MB: pvec -> evec
  short* buf2  = (short*)alloc(RB * 320 * 2);   // 40 MB: pstate -> token
  short* buf3  = (short*)alloc(RB * 320 * 2);   // 40 MB: pre -> h
  short* vtbuf = (short*)alloc(RB * 320 * 2);   // 40 MB: pstate^T -> pre^T

  // weight prep (tiny)
  {
    int t = 320 * 64;
    dim3 g((t + 255) / 256);
    pad_T<<<g, 256, 0, stream>>>(me,  wmeT, 50, 300, 64, t);
    pad_T<<<g, 256, 0, stream>>>(wpt, wptT, 50, 300, 64, t);
    pad_T<<<g, 256, 0, stream>>>(wpg, wpgT, 50, 300, 64, t);
    pad_T<<<g, 256, 0, stream>>>(wps, wpsT, 50, 300, 64, t);
    pad_T<<<g, 256, 0, stream>>>(wex, wexT, 50, 300, 64, t);
  }
  { int t = 320 * 320;  pad_T<<<(t + 255) / 256, 256, 0, stream>>>(W1, w1T, 300, 300, 320, t); }
  { int t = 1024 * 320; pad_T<<<(t + 255) / 256, 256, 0, stream>>>(W2, w2T, 300, 1024, 320, t); }

  dim3 tgrid(16, 5, 64);

  // pvec, pstate (direct past read, fused 2 outputs)
  gemm_small<2, 1, 1><<<512, 512, 0, stream>>>(past, wpgT, bpg, nullptr,
                                               wpsT, bps, nullptr, buf1, buf2);
  // pstate^T
  transpose_pd<<<tgrid, 256, 0, stream>>>(buf2, vtbuf);
  // ptok + token(LN) (direct x read; buf2 dead after transpose)
  gemm_small<2, 1, 4><<<512, 512, 0, stream>>>(x, wptT, bpt, nullptr,
                                               wmeT, lng, lnb, buf0, buf2);
  // attention 1: pre = sigmoid(ptok.pvec^T).pstate
  attn_v6<<<dim3(64, 8), 512, 0, stream>>>(buf0, buf1, vtbuf, nullptr, buf3);
  // evec (pvec dead)
  gemm_small<1, 1, 1><<<512, 512, 0, stream>>>(x, wexT, bex, nullptr,
                                               nullptr, nullptr, nullptr, buf1, nullptr);
  // pre^T
  transpose_pd<<<tgrid, 256, 0, stream>>>(buf3, vtbuf);
  // attention 2: filt = token + sigmoid(evec.pre^T).pre
  attn_v6<<<dim3(64, 8), 512, 0, stream>>>(buf1, buf3, vtbuf, buf2, buf0);

  // MLP: h = relu(filt@W1+b1), out = h@W2+b2
  gemm_ep<320, 2><<<dim3(512, 1), 512, 0, stream>>>(buf0, w1T, 320, b1, 300, buf3, 320);
  gemm_ep<256, 3><<<dim3(512, 4), 512, 0, stream>>>(buf3, w2T, 320, b2, 1024, out, 1024);
}

// Round 8
// 983.560 us; speedup vs baseline: 1.0564x; 1.0564x over previous
//
#include <hip/hip_runtime.h>
#include <hip/hip_bf16.h>
#include <math.h>

// ---------- types ----------
typedef __attribute__((ext_vector_type(8))) short bf16x8;  // 8 bf16 (4 VGPRs)
typedef __attribute__((ext_vector_type(4))) float f32x4;   // MFMA C/D frag

__device__ inline float bf2f(short u) {
  union { float f; unsigned int i; } v;
  v.i = ((unsigned int)(unsigned short)u) << 16;
  return v.f;
}
__device__ inline short f2bf(float f) {
  union { float f; unsigned int i; } v; v.f = f;
  unsigned int r = v.i + 0x7fff + ((v.i >> 16) & 1);  // RNE
  return (short)(r >> 16);
}

// ---------- prep: pad/convert ----------
__global__ void pad_rows(const float* __restrict__ src, short* __restrict__ dst,
                         int C, int Cp, int total) {
  int i = blockIdx.x * 256 + threadIdx.x;
  if (i >= total) return;
  int r = i / Cp, c = i - r * Cp;
  dst[i] = f2bf(c < C ? src[(size_t)r * C + c] : 0.f);
}

__global__ void pad_T(const float* __restrict__ src, short* __restrict__ dst,
                      int K, int N, int Kp, int total) {
  int i = blockIdx.x * 256 + threadIdx.x;
  if (i >= total) return;
  int n = i / Kp, k = i - n * Kp;
  dst[i] = f2bf((k < K && n < N) ? src[(size_t)k * N + n] : 0.f);
}

// ---------- batched transpose: in [64][1024][320] -> out [64][320][1024] ----------
__global__ __launch_bounds__(256) void transpose_pd(const short* __restrict__ in,
                                                    short* __restrict__ out) {
  __shared__ unsigned int T[64][32];  // row p: 32 dwords (64 shorts)
  const int b = blockIdx.z, p0 = blockIdx.x * 64, d0 = blockIdx.y * 64;
  const short* ib = in + (size_t)b * 1024 * 320;
  short* ob = out + (size_t)b * 320 * 1024;
  for (int i = threadIdx.x; i < 512; i += 256) {
    int p = i >> 3, g = i & 7;
    uint4 v = *(const uint4*)&ib[(size_t)(p0 + p) * 320 + d0 + g * 8];
    int s = p & 31;
    T[p][(4 * g + 0) ^ s] = v.x;
    T[p][(4 * g + 1) ^ s] = v.y;
    T[p][(4 * g + 2) ^ s] = v.z;
    T[p][(4 * g + 3) ^ s] = v.w;
  }
  __syncthreads();
  for (int i = threadIdx.x; i < 512; i += 256) {
    int d = i >> 3, g = i & 7;
    int w0 = d >> 1;
    __align__(16) unsigned short tmp[8];
#pragma unroll
    for (int j = 0; j < 8; ++j) {
      int p = g * 8 + j;
      unsigned int val = T[p][w0 ^ (p & 31)];
      tmp[j] = (d & 1) ? (unsigned short)(val >> 16) : (unsigned short)(val & 0xffff);
    }
    *(uint4*)&ob[(size_t)(d0 + d) * 1024 + p0 + g * 8] = *(const uint4*)tmp;
  }
}

// ---------- unified MFMA GEMM (small-K cases, unchanged from R5) ----------
template<int NT, int MODE>
__global__ __launch_bounds__(512) void gemm_ep(
    const short* __restrict__ A, const short* __restrict__ Bt, int K,
    const float* __restrict__ bias, int biasN,
    void* __restrict__ outp, int outStride)
{
  __shared__ __align__(16) short Bst[NT][40];  // [n][k-tile 32], row 80B
  const int tid = threadIdx.x;
  const int wave = tid >> 6, lane = tid & 63;
  const int m = lane & 15, quad = lane >> 4;
  const int row0 = blockIdx.x * 128 + wave * 16;
  const int n0 = blockIdx.y * NT;

  f32x4 zero = {0.f, 0.f, 0.f, 0.f};
  f32x4 acc[NT / 16];
#pragma unroll
  for (int i = 0; i < NT / 16; ++i) acc[i] = zero;

  const short* arow = A + (size_t)(row0 + m) * K;

  for (int k0 = 0; k0 < K; k0 += 32) {
    __syncthreads();
    for (int idx = tid; idx < NT * 4; idx += 512) {
      int n = idx >> 2, kc = (idx & 3) << 3;
      *(uint4*)&Bst[n][kc] = *(const uint4*)&Bt[(size_t)(n0 + n) * K + k0 + kc];
    }
    __syncthreads();
    bf16x8 af = *(const bf16x8*)(arow + k0 + quad * 8);
#pragma unroll
    for (int nt = 0; nt < NT / 16; ++nt) {
      bf16x8 bf = *(const bf16x8*)&Bst[nt * 16 + m][quad * 8];
      acc[nt] = __builtin_amdgcn_mfma_f32_16x16x32_bf16(af, bf, acc[nt], 0, 0, 0);
    }
  }

#pragma unroll
  for (int nt = 0; nt < NT / 16; ++nt) {
#pragma unroll
    for (int r = 0; r < 4; ++r) {
      int row = row0 + quad * 4 + r;
      int col = n0 + nt * 16 + m;
      float v = acc[nt][r];
      if (MODE != 0) v += (col < biasN) ? bias[col] : 0.f;
      if (MODE == 1) v = tanhf(v);
      if (MODE == 2) v = fmaxf(v, 0.f);
      if (MODE == 3)
        ((float*)outp)[(size_t)row * outStride + col] = v;
      else
        ((short*)outp)[(size_t)row * outStride + col] = f2bf(v);
    }
  }
}

// ---------- helpers ----------
__device__ inline void gload16(const short* g, short* l) {
  __builtin_amdgcn_global_load_lds((const __attribute__((address_space(1))) void*)g,
                                   (__attribute__((address_space(3))) void*)l, 16, 0, 0);
}
__device__ inline void block_sync() {
  asm volatile("s_waitcnt vmcnt(0) lgkmcnt(0)" ::: "memory");
  __builtin_amdgcn_s_barrier();
  __builtin_amdgcn_sched_barrier(0);
}

// ---------- big-K GEMM (W1/W2): 32 rows/wave, gload16 dbuf staging ----------
// Each wave computes 2 row-tiles (32 rows) -> each B-frag LDS read feeds 2 MFMAs
// (halves LDS-read traffic vs gemm_ep; W2's floor drops 34 -> 17 us).
// B staged via global_load_lds, double-buffered, ONE barrier per k-step; A-frag
// global loads issued BEFORE the stage-issue so their vmcnt wait doesn't drain
// the prefetch. B 16B-chunk ch stored from source chunk ch^((n>>2)&3) (linear LDS
// dest); read slot = quad^((m>>2)&3) -> 2-way max bank conflict on ds_read_b128.
template<int NT, int MODE>
__global__ __launch_bounds__(512) void gemm_big(
    const short* __restrict__ A, const short* __restrict__ Bt, int K,
    const float* __restrict__ bias, int biasN,
    void* __restrict__ outp, int outStride)
{
  constexpr int NTT = NT / 16;
  constexpr int JCNT = (NT * 4 + 511) / 512;
  __shared__ __align__(16) short Bst[2][NT * 32];

  const int tid = threadIdx.x;
  const int wave = tid >> 6, lane = tid & 63;
  const int m = lane & 15, quad = lane >> 4;
  const int row0 = blockIdx.x * 256 + wave * 32;  // 2 row-tiles per wave
  const int n0 = blockIdx.y * NT;

  // staging descriptors (chunk c = n*4+ch; source chunk pre-swizzled)
  const short* sp[JCNT];
  int sd[JCNT];
#pragma unroll
  for (int j = 0; j < JCNT; ++j) {
    int c = j * 512 + tid;
    if (c < NT * 4) {
      int n = c >> 2, ch = c & 3;
      sp[j] = Bt + (size_t)(n0 + n) * K + ((ch ^ ((n >> 2) & 3)) << 3);
      sd[j] = c << 3;
    }
  }
  auto stage = [&](int it) {
#pragma unroll
    for (int j = 0; j < JCNT; ++j) {
      int c = j * 512 + tid;  // guard wave-uniform (512-granular)
      if (c < NT * 4) gload16(sp[j] + it * 32, &Bst[it & 1][sd[j]]);
    }
  };

  f32x4 zero = {0.f, 0.f, 0.f, 0.f};
  f32x4 acc[2][NTT];
#pragma unroll
  for (int h = 0; h < 2; ++h)
#pragma unroll
    for (int i = 0; i < NTT; ++i) acc[h][i] = zero;

  const short* ar0 = A + (size_t)(row0 + m) * K;
  const short* ar1 = A + (size_t)(row0 + 16 + m) * K;
  const int rch = (quad ^ ((m >> 2) & 3)) << 3;  // swizzled read chunk (per-lane const)

  stage(0);
  block_sync();

  const int KIT = K >> 5;
  for (int it = 0; it < KIT; ++it) {
    // A-frags FIRST (so their wait doesn't drain the prefetch queue)
    bf16x8 a0 = *(const bf16x8*)(ar0 + it * 32 + quad * 8);
    bf16x8 a1 = *(const bf16x8*)(ar1 + it * 32 + quad * 8);
    if (it + 1 < KIT) stage(it + 1);
    const short* Bc = &Bst[it & 1][0];
#pragma unroll
    for (int nt = 0; nt < NTT; ++nt) {
      bf16x8 bf = *(const bf16x8*)&Bc[(nt * 16 + m) * 32 + rch];
      acc[0][nt] = __builtin_amdgcn_mfma_f32_16x16x32_bf16(a0, bf, acc[0][nt], 0, 0, 0);
      acc[1][nt] = __builtin_amdgcn_mfma_f32_16x16x32_bf16(a1, bf, acc[1][nt], 0, 0, 0);
    }
    block_sync();
  }

#pragma unroll
  for (int h = 0; h < 2; ++h)
#pragma unroll
    for (int nt = 0; nt < NTT; ++nt)
#pragma unroll
      for (int r = 0; r < 4; ++r) {
        int row = row0 + h * 16 + quad * 4 + r;
        int col = n0 + nt * 16 + m;
        float v = acc[h][nt][r];
        v += (col < biasN) ? bias[col] : 0.f;
        if (MODE == 2) v = fmaxf(v, 0.f);
        if (MODE == 3)
          ((float*)outp)[(size_t)row * outStride + col] = v;
        else
          ((short*)outp)[(size_t)row * outStride + col] = f2bf(v);
      }
}

// ---------- LayerNorm over first 300 cols of a [rows x 320] bf16 buffer, in place ----------
__global__ __launch_bounds__(256) void ln_rows(short* __restrict__ tp,
                                               const float* __restrict__ g,
                                               const float* __restrict__ bb) {
  const int wave = threadIdx.x >> 6, lane = threadIdx.x & 63;
  const int row = blockIdx.x * 4 + wave;
  short* p = tp + (size_t)row * 320;
  float vals[5], s = 0.f, ss = 0.f;
#pragma unroll
  for (int i = 0; i < 5; ++i) {
    int c = lane + i * 64;
    float v = (c < 300) ? bf2f(p[c]) : 0.f;
    vals[i] = v; s += v; ss += v * v;
  }
#pragma unroll
  for (int off = 32; off > 0; off >>= 1) { s += __shfl_down(s, off); ss += __shfl_down(ss, off); }
  s = __shfl(s, 0); ss = __shfl(ss, 0);
  const float mu = s * (1.f / 300.f);
  const float rstd = rsqrtf(ss * (1.f / 300.f) - mu * mu + 1e-6f);
#pragma unroll
  for (int i = 0; i < 5; ++i) {
    int c = lane + i * 64;
    float v = (c < 300) ? (g[c] * (vals[i] - mu) * rstd + bb[c]) : 0.f;
    p[c] = f2bf(v);
  }
}

// ---------- fused sigmoid-attention v6 (unchanged, verified) ----------
__global__ __launch_bounds__(512, 2) void attn_v6(
    const short* __restrict__ Qm, const short* __restrict__ Km,
    const short* __restrict__ VT, const short* __restrict__ tokp,
    short* __restrict__ Outp)
{
  __shared__ __align__(16) short KsL[2][10240];  // [32 p][320 d], chunk^(p&7)
  __shared__ __align__(16) short VsL[2][10240];  // [320 d][32 p], chunk^(d&3)

  const int tid = threadIdx.x;
  const int wave = tid >> 6, lane = tid & 63;
  const int m = lane & 15, quad = lane >> 4;
  const int b = blockIdx.x;
  const int qrow0 = b * 1024 + blockIdx.y * 128;
  const size_t kbase = (size_t)b * 1024 * 320;
  const short* vtb = VT + (size_t)b * 320 * 1024;

  const short* src[5];
  int dst[5];
#pragma unroll
  for (int j = 0; j < 5; ++j) {
    int c = j * 512 + tid;
    if (c < 1280) {
      int p = c / 40, ch = c - p * 40;
      src[j] = Km + kbase + (size_t)p * 320 + ((ch ^ (p & 7)) << 3);
      dst[j] = c << 3;
    } else {
      int cv = c - 1280;
      int d = cv >> 2, ch = cv & 3;
      src[j] = vtb + (size_t)d * 1024 + ((ch ^ (d & 3)) << 3);
      dst[j] = cv << 3;
    }
  }
  const bool j2K = (wave < 4);

  auto stage = [&](int pt) {
    const int bb = pt & 1;
    gload16(src[0] + (size_t)pt * 10240, &KsL[bb][dst[0]]);
    gload16(src[1] + (size_t)pt * 10240, &KsL[bb][dst[1]]);
    if (j2K) gload16(src[2] + (size_t)pt * 10240, &KsL[bb][dst[2]]);
    else     gload16(src[2] + (size_t)pt * 32,    &VsL[bb][dst[2]]);
    gload16(src[3] + (size_t)pt * 32, &VsL[bb][dst[3]]);
    gload16(src[4] + (size_t)pt * 32, &VsL[bb][dst[4]]);
  };

  bf16x8 qf[10];
  const short* qb = Qm + (size_t)(qrow0 + wave * 16 + m) * 320;
#pragma unroll
  for (int c = 0; c < 10; ++c)
    qf[c] = *(const bf16x8*)(qb + c * 32 + quad * 8);

  f32x4 zero = {0.f, 0.f, 0.f, 0.f};
  f32x4 o[20];
#pragma unroll
  for (int i = 0; i < 20; ++i) o[i] = zero;

  const int vch = (quad ^ (m & 3)) << 3;
  const unsigned oddq = (unsigned)(quad & 1);

  stage(0);
  block_sync();

  for (int pt = 0; pt < 32; ++pt) {
    if (pt < 31) stage(pt + 1);
    const short* Kc = &KsL[pt & 1][0];
    const short* Vc = &VsL[pt & 1][0];

    f32x4 sl = zero, sh = zero;
#pragma unroll
    for (int c = 0; c < 10; ++c) {
      int ch0 = ((4 * c + quad) ^ (m & 7)) << 3;
      bf16x8 k0 = *(const bf16x8*)&Kc[m * 320 + ch0];
      bf16x8 k1 = *(const bf16x8*)&Kc[(m + 16) * 320 + ch0];
      sl = __builtin_amdgcn_mfma_f32_16x16x32_bf16(k0, qf[c], sl, 0, 0, 0);
      sh = __builtin_amdgcn_mfma_f32_16x16x32_bf16(k1, qf[c], sh, 0, 0, 0);
    }

    float e0[4], e1[4];
#pragma unroll
    for (int r = 0; r < 4; ++r) {
      e0[r] = 1.f / (1.f + __expf(-sl[r]));
      e1[r] = 1.f / (1.f + __expf(-sh[r]));
    }
    int w0, w1, w2, w3;
    asm("v_cvt_pk_bf16_f32 %0, %1, %2" : "=v"(w0) : "v"(e0[0]), "v"(e0[1]));
    asm("v_cvt_pk_bf16_f32 %0, %1, %2" : "=v"(w1) : "v"(e0[2]), "v"(e0[3]));
    asm("v_cvt_pk_bf16_f32 %0, %1, %2" : "=v"(w2) : "v"(e1[0]), "v"(e1[1]));
    asm("v_cvt_pk_bf16_f32 %0, %1, %2" : "=v"(w3) : "v"(e1[2]), "v"(e1[3]));

    int x0 = w0, y0 = w2, x1 = w1, y1 = w3;
    asm volatile("v_permlane32_swap_b32 %0, %1" : "+v"(x0), "+v"(y0));
    asm volatile("v_permlane32_swap_b32 %0, %1" : "+v"(x1), "+v"(y1));
    int sx0 = __builtin_amdgcn_ds_swizzle(x0, 0x401f);
    int sy0 = __builtin_amdgcn_ds_swizzle(y0, 0x401f);
    int sx1 = __builtin_amdgcn_ds_swizzle(x1, 0x401f);
    int sy1 = __builtin_amdgcn_ds_swizzle(y1, 0x401f);
    union { int i[4]; bf16x8 v; } pu;
    pu.i[0] = oddq ? sy0 : x0;
    pu.i[1] = oddq ? sy1 : x1;
    pu.i[2] = oddq ? y0 : sx0;
    pu.i[3] = oddq ? y1 : sx1;
    bf16x8 pa = pu.v;

#pragma unroll
    for (int dt = 0; dt < 20; ++dt) {
      bf16x8 vb = *(const bf16x8*)&Vc[(dt * 16 + m) * 32 + vch];
      o[dt] = __builtin_amdgcn_mfma_f32_16x16x32_bf16(pa, vb, o[dt], 0, 0, 0);
    }

    block_sync();
  }

#pragma unroll
  for (int dt = 0; dt < 20; ++dt)
#pragma unroll
    for (int r = 0; r < 4; ++r) {
      const size_t row = (size_t)qrow0 + wave * 16 + quad * 4 + r;
      const int col = dt * 16 + m;
      float val = o[dt][r];
      if (tokp) val += bf2f(tokp[row * 320 + col]);
      Outp[row * 320 + col] = f2bf(val);
    }
}

// ---------- launch ----------
extern "C" void kernel_launch(void* const* d_in, const int* in_sizes, int n_in,
                              void* d_out, int out_size, void* d_ws, size_t ws_size,
                              hipStream_t stream)
{
  const float* x    = (const float*)d_in[0];
  const float* me   = (const float*)d_in[1];
  const float* past = (const float*)d_in[2];
  const float* wpt  = (const float*)d_in[3];
  const float* bpt  = (const float*)d_in[4];
  const float* wpg  = (const float*)d_in[5];
  const float* bpg  = (const float*)d_in[6];
  const float* wps  = (const float*)d_in[7];
  const float* bps  = (const float*)d_in[8];
  const float* wex  = (const float*)d_in[9];
  const float* bex  = (const float*)d_in[10];
  const float* lng  = (const float*)d_in[11];
  const float* lnb  = (const float*)d_in[12];
  const float* W1   = (const float*)d_in[13];
  const float* b1   = (const float*)d_in[14];
  const float* W2   = (const float*)d_in[15];
  const float* b2   = (const float*)d_in[16];
  float* out = (float*)d_out;

  // ---- workspace (~226 MB) ----
  char* ws = (char*)d_ws;
  size_t off = 0;
  auto alloc = [&](size_t bytes) -> char* {
    char* p = ws + off; off += (bytes + 255) & ~(size_t)255; return p;
  };
  const size_t RB = 65536ull;
  short* xp    = (short*)alloc(RB * 64 * 2);    //  8 MB
  short* pastp = (short*)alloc(RB * 64 * 2);    //  8 MB
  short* wmeT  = (short*)alloc(320 * 64 * 2);
  short* wptT  = (short*)alloc(320 * 64 * 2);
  short* wpgT  = (short*)alloc(320 * 64 * 2);
  short* wpsT  = (short*)alloc(320 * 64 * 2);
  short* wexT  = (short*)alloc(320 * 64 * 2);
  short* w1T   = (short*)alloc(320 * 320 * 2);
  short* w2T   = (short*)alloc(1024ull * 320 * 2);
  short* buf0  = (short*)alloc(RB * 320 * 2);   // 40 MB: ptok -> filt
  short* buf1  = (short*)alloc(RB * 320 * 2);   // 40 MB: pvec -> token
  short* buf2  = (short*)alloc(RB * 320 * 2);   // 40 MB: pstate -> evec
  short* buf3  = (short*)alloc(RB * 320 * 2);   // 40 MB: pre -> h
  short* vtbuf = (short*)alloc(RB * 320 * 2);   // 40 MB: pstate^T -> pre^T

  // prep
  {
    int total = 65536 * 64;
    pad_rows<<<dim3((total + 255) / 256), 256, 0, stream>>>(x, xp, 50, 64, total);
    pad_rows<<<dim3((total + 255) / 256), 256, 0, stream>>>(past, pastp, 50, 64, total);
  }
  {
    int t = 320 * 64;
    dim3 g((t + 255) / 256);
    pad_T<<<g, 256, 0, stream>>>(me,  wmeT, 50, 300, 64, t);
    pad_T<<<g, 256, 0, stream>>>(wpt, wptT, 50, 300, 64, t);
    pad_T<<<g, 256, 0, stream>>>(wpg, wpgT, 50, 300, 64, t);
    pad_T<<<g, 256, 0, stream>>>(wps, wpsT, 50, 300, 64, t);
    pad_T<<<g, 256, 0, stream>>>(wex, wexT, 50, 300, 64, t);
  }
  { int t = 320 * 320;  pad_T<<<(t + 255) / 256, 256, 0, stream>>>(W1, w1T, 300, 300, 320, t); }
  { int t = 1024 * 320; pad_T<<<(t + 255) / 256, 256, 0, stream>>>(W2, w2T, 300, 1024, 320, t); }

  dim3 g512(512, 1);
  dim3 tgrid(16, 5, 64);
  // attention-1 operands
  gemm_ep<320, 1><<<g512, 512, 0, stream>>>(xp,    wptT, 64, bpt, 300, buf0, 320); // ptok
  gemm_ep<320, 1><<<g512, 512, 0, stream>>>(pastp, wpgT, 64, bpg, 300, buf1, 320); // pvec
  gemm_ep<320, 1><<<g512, 512, 0, stream>>>(pastp, wpsT, 64, bps, 300, buf2, 320); // pstate
  transpose_pd<<<tgrid, 256, 0, stream>>>(buf2, vtbuf);                            // pstate^T

  // attention 1: pre = sigmoid(ptok.pvec^T).pstate
  attn_v6<<<dim3(64, 8), 512, 0, stream>>>(buf0, buf1, vtbuf, nullptr, buf3);

  // token (buf1: pvec dead), evec (buf2: pstate dead)
  gemm_ep<320, 0><<<g512, 512, 0, stream>>>(xp, wmeT, 64, nullptr, 0, buf1, 320);
  ln_rows<<<16384, 256, 0, stream>>>(buf1, lng, lnb);
  gemm_ep<320, 1><<<g512, 512, 0, stream>>>(xp, wexT, 64, bex, 300, buf2, 320);

  // pre^T (overwrites pstate^T)
  transpose_pd<<<tgrid, 256, 0, stream>>>(buf3, vtbuf);

  // attention 2: filt = token + sigmoid(evec.pre^T).pre   (buf0: ptok dead)
  attn_v6<<<dim3(64, 8), 512, 0, stream>>>(buf2, buf3, vtbuf, buf1, buf0);

  // MLP: h = relu(filt@W1+b1), out = h@W2+b2  (gemm_big: 32 rows/wave, dbuf)
  gemm_big<320, 2><<<dim3(256, 1), 512, 0, stream>>>(buf0, w1T, 320, b1, 300, buf3, 320);
  gemm_big<256, 3><<<dim3(256, 4), 512, 0, stream>>>(buf3, w2T, 320, b2, 1024, out, 1024);
}